// Round 4
// baseline (628.489 us; speedup 1.0000x reference)
//
#include <hip/hip_runtime.h>
#include <hip/hip_bf16.h>

// Problem constants
constexpr int B_ = 2, S_ = 1024, H_ = 2048;
constexpr int NH_ = 16, NKV_ = 8, HD_ = 128, GROUPS_ = 2;
constexpr int TOPK_ = 409;  // int(0.4 * 1024)
constexpr int QSTRIDE = NH_ * HD_;   // 2048
constexpr int KSTRIDE = NKV_ * HD_;  // 1024
constexpr int QB_ = 16;              // queries per attention block (full MFMA M)

typedef __attribute__((ext_vector_type(8))) short short8;
typedef __attribute__((ext_vector_type(4))) float f32x4;
typedef __attribute__((ext_vector_type(4))) unsigned u32x4;
typedef __attribute__((ext_vector_type(4))) unsigned short ush4;

__device__ inline unsigned fkey(float x) {
  unsigned u = __float_as_uint(x);
  return (u & 0x80000000u) ? ~u : (u | 0x80000000u);
}
__device__ inline unsigned short bf16_rne(float x) {
  unsigned u = __float_as_uint(x);
  unsigned r = u + 0x7FFFu + ((u >> 16) & 1u);
  return (unsigned short)(r >> 16);
}
__device__ inline float bf16_to_f(unsigned short h) {
  return __uint_as_float((unsigned)h << 16);
}
// float -> (hi bf16 << 16) | lo bf16   (RNE split: x ~= hi + lo)
__device__ inline unsigned packsplit(float x) {
  unsigned u = __float_as_uint(x);
  unsigned r = (u + 0x7FFFu + ((u >> 16) & 1u)) & 0xFFFF0000u;
  float rem = x - __uint_as_float(r);
  unsigned v = __float_as_uint(rem);
  unsigned l = (v + 0x7FFFu + ((v >> 16) & 1u)) >> 16;
  return r | l;
}

// perm selectors: dst = {src1.b2,src1.b3,src0.b2,src0.b3} (hi) / low bytes (lo)
#define PERM_HI 0x07060302u
#define PERM_LO 0x05040100u

// 8 packed dwords (16B-aligned LDS/global) -> hi/lo bf16 fragments
__device__ inline void unpack8(const unsigned* p, short8& hi, short8& lo) {
  u32x4 w0 = *(const u32x4*)p;
  u32x4 w1 = *(const u32x4*)(p + 4);
  u32x4 h, l;
  h.x = __builtin_amdgcn_perm(w0.y, w0.x, PERM_HI);
  h.y = __builtin_amdgcn_perm(w0.w, w0.z, PERM_HI);
  h.z = __builtin_amdgcn_perm(w1.y, w1.x, PERM_HI);
  h.w = __builtin_amdgcn_perm(w1.w, w1.z, PERM_HI);
  l.x = __builtin_amdgcn_perm(w0.y, w0.x, PERM_LO);
  l.y = __builtin_amdgcn_perm(w0.w, w0.z, PERM_LO);
  l.z = __builtin_amdgcn_perm(w1.y, w1.x, PERM_LO);
  l.w = __builtin_amdgcn_perm(w1.w, w1.z, PERM_LO);
  hi = *(short8*)&h;
  lo = *(short8*)&l;
}
// same, from two registers (globals already loaded)
__device__ inline void unpack8r(u32x4 w0, u32x4 w1, short8& hi, short8& lo) {
  u32x4 h, l;
  h.x = __builtin_amdgcn_perm(w0.y, w0.x, PERM_HI);
  h.y = __builtin_amdgcn_perm(w0.w, w0.z, PERM_HI);
  h.z = __builtin_amdgcn_perm(w1.y, w1.x, PERM_HI);
  h.w = __builtin_amdgcn_perm(w1.w, w1.z, PERM_HI);
  l.x = __builtin_amdgcn_perm(w0.y, w0.x, PERM_LO);
  l.y = __builtin_amdgcn_perm(w0.w, w0.z, PERM_LO);
  l.z = __builtin_amdgcn_perm(w1.y, w1.x, PERM_LO);
  l.w = __builtin_amdgcn_perm(w1.w, w1.z, PERM_LO);
  hi = *(short8*)&h;
  lo = *(short8*)&l;
}

// ---------------------------------------------------------------------------
// Split-precision bf16 MFMA GEMM body: C[m,n] = sum_k A[m,k]*W[n,k] + bias[n]
// Tile: (TI*32) x 128, BK=32, 256 threads (4 waves).
// Double-buffered LDS staging, ONE barrier per K-step, register prefetch.
// VT=true: write C transposed per (b,kv-head) slab as [dim][token] (float4).
// ---------------------------------------------------------------------------
template <int TI, bool VT>
__device__ __forceinline__ void gemm_split_body(
    const float* __restrict__ A, const float* __restrict__ W,
    const float* __restrict__ bias, float* __restrict__ C, int ldc, int c0,
    int K, int m0) {
  __shared__ unsigned short Ah[2][TI * 32 * 32];
  __shared__ unsigned short Al[2][TI * 32 * 32];
  __shared__ unsigned short Wh[2][128 * 32];
  __shared__ unsigned short Wl[2][128 * 32];
  const int tid = threadIdx.x;
  const int lane = tid & 63, wid = tid >> 6;
  const int wrow = (wid >> 1) * (TI * 16), wcol = (wid & 1) * 64;
  const int fm = lane & 15, quad = lane >> 4;
  const int srow = tid >> 3;        // 0..31
  const int skq = (tid & 7) * 4;    // 0,4,..,28
  f32x4 acc[TI][4] = {};
  float4 avr[TI], wvr[4];

  auto loadAW = [&](int k0) {
#pragma unroll
    for (int r = 0; r < TI; ++r)
      avr[r] = *(const float4*)&A[(size_t)(m0 + srow + 32 * r) * K + k0 + skq];
#pragma unroll
    for (int r = 0; r < 4; ++r)
      wvr[r] = *(const float4*)&W[(size_t)(srow + 32 * r) * K + k0 + skq];
  };
  auto convWrite = [&](int buf) {
#pragma unroll
    for (int r = 0; r < TI; ++r) {
      const int row = srow + 32 * r;
      const int off =
          row * 32 + ((((skq >> 3) ^ ((row >> 1) & 3)) << 3) | (skq & 7));
      unsigned short h0 = bf16_rne(avr[r].x), h1 = bf16_rne(avr[r].y),
                     h2 = bf16_rne(avr[r].z), h3 = bf16_rne(avr[r].w);
      ush4 hv; hv.x = h0; hv.y = h1; hv.z = h2; hv.w = h3;
      ush4 lv;
      lv.x = bf16_rne(avr[r].x - bf16_to_f(h0));
      lv.y = bf16_rne(avr[r].y - bf16_to_f(h1));
      lv.z = bf16_rne(avr[r].z - bf16_to_f(h2));
      lv.w = bf16_rne(avr[r].w - bf16_to_f(h3));
      *(ush4*)&Ah[buf][off] = hv;
      *(ush4*)&Al[buf][off] = lv;
    }
#pragma unroll
    for (int r = 0; r < 4; ++r) {
      const int row = srow + 32 * r;
      const int off =
          row * 32 + ((((skq >> 3) ^ ((row >> 1) & 3)) << 3) | (skq & 7));
      unsigned short g0 = bf16_rne(wvr[r].x), g1 = bf16_rne(wvr[r].y),
                     g2 = bf16_rne(wvr[r].z), g3 = bf16_rne(wvr[r].w);
      ush4 hv; hv.x = g0; hv.y = g1; hv.z = g2; hv.w = g3;
      ush4 lv;
      lv.x = bf16_rne(wvr[r].x - bf16_to_f(g0));
      lv.y = bf16_rne(wvr[r].y - bf16_to_f(g1));
      lv.z = bf16_rne(wvr[r].z - bf16_to_f(g2));
      lv.w = bf16_rne(wvr[r].w - bf16_to_f(g3));
      *(ush4*)&Wh[buf][off] = hv;
      *(ush4*)&Wl[buf][off] = lv;
    }
  };

  loadAW(0);
  convWrite(0);
  __syncthreads();
  int cur = 0;
  for (int k0 = 0; k0 < K; k0 += 32) {
    const bool more = (k0 + 32) < K;
    if (more) loadAW(k0 + 32);  // issue early; consumed by convWrite below
    short8 ah[TI], al[TI], bh[4], bl[4];
#pragma unroll
    for (int ti = 0; ti < TI; ++ti) {
      const int r = wrow + 16 * ti + fm;
      const int off = r * 32 + ((quad ^ ((r >> 1) & 3)) << 3);
      ah[ti] = *(const short8*)&Ah[cur][off];
      al[ti] = *(const short8*)&Al[cur][off];
    }
#pragma unroll
    for (int tj = 0; tj < 4; ++tj) {
      const int r = wcol + 16 * tj + fm;
      const int off = r * 32 + ((quad ^ ((r >> 1) & 3)) << 3);
      bh[tj] = *(const short8*)&Wh[cur][off];
      bl[tj] = *(const short8*)&Wl[cur][off];
    }
#pragma unroll
    for (int ti = 0; ti < TI; ++ti)
#pragma unroll
      for (int tj = 0; tj < 4; ++tj) {
        acc[ti][tj] = __builtin_amdgcn_mfma_f32_16x16x32_bf16(
            ah[ti], bh[tj], acc[ti][tj], 0, 0, 0);
        acc[ti][tj] = __builtin_amdgcn_mfma_f32_16x16x32_bf16(
            ah[ti], bl[tj], acc[ti][tj], 0, 0, 0);
        acc[ti][tj] = __builtin_amdgcn_mfma_f32_16x16x32_bf16(
            al[ti], bh[tj], acc[ti][tj], 0, 0, 0);
      }
    if (more) convWrite(cur ^ 1);
    __syncthreads();
    cur ^= 1;
  }
  if constexpr (VT) {
    // write transposed: vT[b][head][dim][token], 4 consecutive tokens/lane
#pragma unroll
    for (int tj = 0; tj < 4; ++tj) {
      float bsv = bias[wcol + 16 * tj + fm];
#pragma unroll
      for (int ti = 0; ti < TI; ++ti) {
        int tok = m0 + wrow + 16 * ti + quad * 4;
        int ncol = c0 + wcol + 16 * tj + fm;  // 0..1023 within v N-space
        int head = ncol >> 7, dim = ncol & 127;
        int bb = tok >> 10, ss = tok & 1023;
        float4 ov;
        ov.x = acc[ti][tj][0] + bsv;
        ov.y = acc[ti][tj][1] + bsv;
        ov.z = acc[ti][tj][2] + bsv;
        ov.w = acc[ti][tj][3] + bsv;
        *(float4*)&C[(((size_t)(bb * NKV_ + head)) * HD_ + dim) * S_ + ss] = ov;
      }
    }
  } else {
#pragma unroll
    for (int tj = 0; tj < 4; ++tj) {
      float bsv = bias[wcol + 16 * tj + fm];
#pragma unroll
      for (int ti = 0; ti < TI; ++ti) {
        int mrow = m0 + wrow + 16 * ti + quad * 4;
        int ncol = c0 + wcol + 16 * tj + fm;
#pragma unroll
        for (int reg = 0; reg < 4; ++reg)
          C[(size_t)(mrow + reg) * ldc + ncol] = acc[ti][tj][reg] + bsv;
      }
    }
  }
}

// Fused QKV projection: N-space = [q 0..2048) [k 2048..3072) [v 3072..4096)
__global__ __launch_bounds__(256) void gemm_qkv(
    const float* __restrict__ hidden, const float* __restrict__ wq,
    const float* __restrict__ bq, const float* __restrict__ wk,
    const float* __restrict__ bk, const float* __restrict__ wv,
    const float* __restrict__ bv, float* __restrict__ q, float* __restrict__ k,
    float* __restrict__ v) {
  const int n0 = blockIdx.x * 128, m0 = blockIdx.y * 128;
  if (n0 < QSTRIDE) {
    gemm_split_body<4, false>(hidden, wq + (size_t)n0 * H_, bq + n0, q,
                              QSTRIDE, n0, H_, m0);
  } else if (n0 < QSTRIDE + KSTRIDE) {
    int nn = n0 - QSTRIDE;
    gemm_split_body<4, false>(hidden, wk + (size_t)nn * H_, bk + nn, k,
                              KSTRIDE, nn, H_, m0);
  } else {
    int nn = n0 - QSTRIDE - KSTRIDE;
    gemm_split_body<4, true>(hidden, wv + (size_t)nn * H_, bv + nn, v, 0, nn,
                             H_, m0);
  }
}

// Generic GEMM (used for out-proj with TI=2 -> 64-row tiles, grid 512)
template <int TI>
__global__ __launch_bounds__(256) void gemm_split_k(
    const float* __restrict__ A, const float* __restrict__ W,
    const float* __restrict__ bias, float* __restrict__ C, int N, int K) {
  const int n0 = blockIdx.x * 128, m0 = blockIdx.y * (TI * 32);
  gemm_split_body<TI, false>(A, W + (size_t)n0 * K, bias + n0, C, N, n0, K,
                             m0);
}

// ---------------------------------------------------------------------------
// RoPE (q,k) + split-pack IN PLACE as (hi<<16|lo) dwords.
// q,k: rope+pack (layout unchanged). v: elementwise pack of the TRANSPOSED
// slab written by gemm_qkv ([b][head][dim][token]).
// grid (S, B), block 256.
// ---------------------------------------------------------------------------
__global__ __launch_bounds__(256) void rope_pack(float* __restrict__ qtmp,
                                                 float* __restrict__ ktmp,
                                                 float* __restrict__ vtmp,
                                                 const int* __restrict__ pos_ids) {
  const int s = blockIdx.x, b = blockIdx.y;
  const int t = threadIdx.x;
  __shared__ float fsh[64];
  if (t < 64) fsh[t] = (float)(1.0 / pow(1.0e6, (double)t / 64.0));
  __syncthreads();
  const int pos = pos_ids[b * S_ + s];
#pragma unroll
  for (int it = 0; it < 6; ++it) {
    const int p = t + 256 * it;   // 0..1535  (slots 0..23: q then k)
    const int slot = p >> 6;
    const int d = p & 63;
    float* base = (slot < NH_)
                      ? qtmp + (size_t)(b * S_ + s) * QSTRIDE + slot * HD_
                      : ktmp + (size_t)(b * S_ + s) * KSTRIDE + (slot - NH_) * HD_;
    float x = base[d], y = base[d + 64];
    unsigned* up = (unsigned*)base;
    float ang = (float)pos * fsh[d];
    float c = cosf(ang), sn = sinf(ang);
    up[d] = packsplit(x * c - y * sn);
    up[d + 64] = packsplit(y * c + x * sn);
  }
  // v (transposed layout): pack 1024 dwords per (b,s) block, linear over slab
  {
    float* vb4 = vtmp + ((size_t)(b * S_ + s) * 1024) + t * 4;
    float4 xv = *(float4*)vb4;
    u32x4 pk;
    pk.x = packsplit(xv.x);
    pk.y = packsplit(xv.y);
    pk.z = packsplit(xv.z);
    pk.w = packsplit(xv.w);
    *(u32x4*)vb4 = pk;
  }
}

// ---------------------------------------------------------------------------
// Sparse attention v7 (MFMA): one block per (b, h, 16 queries), 512 threads.
// K fragments direct from global; V fragments direct from TRANSPOSED global
// (contiguous 32B/lane). Exact top-k via register-resident 32-round bisection
// (no LDS atomics; both wave queries share one packed shuffle reduction).
// 2 block-wide barriers. Bit-identical numerics to v6.
// ---------------------------------------------------------------------------
constexpr int SCW = 1030;   // sc row stride (pad: 1024+6)

__global__ __launch_bounds__(512, 4) void attn_kernel(
    unsigned* __restrict__ qpk, const unsigned* __restrict__ kpk,
    const unsigned* __restrict__ vpk) {
  const int q0 = blockIdx.x * QB_;
  const int h = blockIdx.y, b = blockIdx.z, g = h / GROUPS_;
  const int t = threadIdx.x, lane = t & 63, wid = t >> 6;  // wid 0..7
  const int fm = lane & 15, quad = lane >> 4;

  __shared__ float sc[QB_ * SCW];       // 65.9 KB: fp32 scores -> packed probs
  __shared__ float redmx[8][QB_];
  __shared__ float Zsh[QB_];
  const float scale = 0.08838834764831845f;  // 1/sqrt(128)

  // ---- Q A-fragments straight from global (row fm = query within block) ----
  short8 qh[4], ql[4];
  {
    const unsigned* qrow =
        qpk + (size_t)(b * S_ + q0 + fm) * QSTRIDE + h * HD_;
#pragma unroll
    for (int ks = 0; ks < 4; ++ks) {
      u32x4 a0 = *(const u32x4*)&qrow[ks * 32 + quad * 8];
      u32x4 a1 = *(const u32x4*)&qrow[ks * 32 + quad * 8 + 4];
      unpack8r(a0, a1, qh[ks], ql[ks]);
    }
  }

  // ---- QK^T over 8 tiles of 128 keys; K fragments direct from global ----
  const unsigned* kg = kpk + (size_t)(b * S_) * KSTRIDE + g * HD_;
  f32x4 mxacc = {-1e30f, -1e30f, -1e30f, -1e30f};
  for (int tile = 0; tile < 8; ++tile) {
    const unsigned* kr = kg + (size_t)(tile * 128 + wid * 16 + fm) * KSTRIDE;
    u32x4 kreg[8];
#pragma unroll
    for (int ks = 0; ks < 4; ++ks) {
      kreg[2 * ks] = *(const u32x4*)&kr[ks * 32 + quad * 8];
      kreg[2 * ks + 1] = *(const u32x4*)&kr[ks * 32 + quad * 8 + 4];
    }
    f32x4 acc = {0.f, 0.f, 0.f, 0.f};
#pragma unroll
    for (int ks = 0; ks < 4; ++ks) {
      short8 bh, bl;
      unpack8r(kreg[2 * ks], kreg[2 * ks + 1], bh, bl);
      acc = __builtin_amdgcn_mfma_f32_16x16x32_bf16(qh[ks], bh, acc, 0, 0, 0);
      acc = __builtin_amdgcn_mfma_f32_16x16x32_bf16(qh[ks], bl, acc, 0, 0, 0);
      acc = __builtin_amdgcn_mfma_f32_16x16x32_bf16(ql[ks], bh, acc, 0, 0, 0);
    }
    // C/D: col = fm (key), row = quad*4+reg (all 16 rows = queries)
    const int key = tile * 128 + wid * 16 + fm;
#pragma unroll
    for (int reg = 0; reg < 4; ++reg) {
      float sval = acc[reg] * scale;
      sc[(quad * 4 + reg) * SCW + key] = sval;
      mxacc[reg] = fmaxf(mxacc[reg], sval);
    }
  }
  // per-wave row max: reduce across fm lanes (quad bits untouched)
#pragma unroll
  for (int o = 1; o < 16; o <<= 1) {
    mxacc[0] = fmaxf(mxacc[0], __shfl_xor(mxacc[0], o));
    mxacc[1] = fmaxf(mxacc[1], __shfl_xor(mxacc[1], o));
    mxacc[2] = fmaxf(mxacc[2], __shfl_xor(mxacc[2], o));
    mxacc[3] = fmaxf(mxacc[3], __shfl_xor(mxacc[3], o));
  }
  if (fm == 0) {
#pragma unroll
    for (int reg = 0; reg < 4; ++reg) redmx[wid][quad * 4 + reg] = mxacc[reg];
  }
  __syncthreads();  // barrier 1: sc + redmx complete (all waves)

  // ---- exact top-k threshold via register bisection (both wave queries) ----
  // threshold T = max{T : #(fkey >= T) >= k} = k-th largest key (ties incl.)
  unsigned curA = 0u, curB = 0u;
  {
    unsigned uvA[16], uvB[16];
#pragma unroll
    for (int j = 0; j < 16; ++j)
      uvA[j] = fkey(sc[(2 * wid) * SCW + lane + 64 * j]);
#pragma unroll
    for (int j = 0; j < 16; ++j)
      uvB[j] = fkey(sc[(2 * wid + 1) * SCW + lane + 64 * j]);
    for (int bit = 31; bit >= 0; --bit) {
      const unsigned m = 1u << bit;
      const unsigned cA = curA | m, cB = curB | m;
      int cnt = 0;
#pragma unroll
      for (int j = 0; j < 16; ++j) cnt += (uvA[j] >= cA) ? 1 : 0;
#pragma unroll
      for (int j = 0; j < 16; ++j) cnt += (uvB[j] >= cB) ? (1 << 16) : 0;
#pragma unroll
      for (int off = 1; off < 64; off <<= 1) cnt += __shfl_xor(cnt, off);
      if ((cnt & 0xFFFF) >= TOPK_) curA = cA;
      if ((cnt >> 16) >= TOPK_) curB = cB;
    }
  }
  const unsigned pref = (lane >= 32) ? curB : curA;  // row qi = t>>5

  // ---- masked softmax numerators; pack P in place as hi|lo dwords ----
  // wave wid owns sc rows 2wid, 2wid+1 (the same rows it selected).
  {
    const int qi = t >> 5, li = t & 31;  // 32 threads per query row
    const float mx =
        fmaxf(fmaxf(fmaxf(redmx[0][qi], redmx[1][qi]),
                    fmaxf(redmx[2][qi], redmx[3][qi])),
              fmaxf(fmaxf(redmx[4][qi], redmx[5][qi]),
                    fmaxf(redmx[6][qi], redmx[7][qi])));
    unsigned* scp = (unsigned*)&sc[qi * SCW];
    float zloc = 0.f;
#pragma unroll 2
    for (int j = 0; j < 8; ++j) {
      int i4 = li * 4 + 128 * j;
      f32x4 sv = *(const f32x4*)&sc[qi * SCW + i4];
      u32x4 pk;
      float p0 = (fkey(sv.x) >= pref) ? __expf(sv.x - mx) : 0.0f;
      float p1 = (fkey(sv.y) >= pref) ? __expf(sv.y - mx) : 0.0f;
      float p2 = (fkey(sv.z) >= pref) ? __expf(sv.z - mx) : 0.0f;
      float p3 = (fkey(sv.w) >= pref) ? __expf(sv.w - mx) : 0.0f;
      zloc += p0 + p1 + p2 + p3;
      pk.x = packsplit(p0); pk.y = packsplit(p1);
      pk.z = packsplit(p2); pk.w = packsplit(p3);
      *(u32x4*)&scp[i4] = pk;
    }
#pragma unroll
    for (int off = 1; off < 32; off <<= 1) zloc += __shfl_xor(zloc, off);
    if (li == 0) Zsh[qi] = zloc;
  }
  __syncthreads();  // barrier 2: packed P + Zsh visible to all waves

  // ---- P.V over 8 tiles of 128 keys; V^T fragments direct from global ----
  const unsigned* scp2 = (const unsigned*)sc;
  const int dim = wid * 16 + fm;  // output dim for this lane
  const unsigned* vgT =
      vpk + ((size_t)(b * NKV_ + g) * HD_ + dim) * S_;  // [dim][token]
  f32x4 oacc = {0.f, 0.f, 0.f, 0.f};
  for (int tile = 0; tile < 8; ++tile) {
#pragma unroll
    for (int ks = 0; ks < 4; ++ks) {
      short8 ph, pl;
      unpack8(&scp2[fm * SCW + tile * 128 + ks * 32 + quad * 8], ph, pl);
      const unsigned* vr = vgT + tile * 128 + ks * 32 + quad * 8;
      u32x4 b0 = *(const u32x4*)vr;
      u32x4 b1 = *(const u32x4*)(vr + 4);
      short8 vh, vl;
      unpack8r(b0, b1, vh, vl);
      oacc = __builtin_amdgcn_mfma_f32_16x16x32_bf16(ph, vh, oacc, 0, 0, 0);
      oacc = __builtin_amdgcn_mfma_f32_16x16x32_bf16(ph, vl, oacc, 0, 0, 0);
      oacc = __builtin_amdgcn_mfma_f32_16x16x32_bf16(pl, vh, oacc, 0, 0, 0);
    }
  }

  // ---- epilogue: row = quad*4+reg (all 16), col = wid*16 + fm ----
#pragma unroll
  for (int reg = 0; reg < 4; ++reg) {
    const int q = quad * 4 + reg;
    const float invZ = 1.0f / Zsh[q];  // Z >= 1 structurally
    float* outp = (float*)qpk + (size_t)(b * S_ + q0 + q) * QSTRIDE + h * HD_;
    outp[dim] = oacc[reg] * invZ;
  }
}

// ---------------------------------------------------------------------------
extern "C" void kernel_launch(void* const* d_in, const int* in_sizes, int n_in,
                              void* d_out, int out_size, void* d_ws,
                              size_t ws_size, hipStream_t stream) {
  // All tensors are float32 per the reference; position_ids is int32.
  const float* hidden = (const float*)d_in[0];
  const float* wq = (const float*)d_in[1];
  const float* bq = (const float*)d_in[2];
  const float* wk = (const float*)d_in[3];
  const float* bk = (const float*)d_in[4];
  const float* wv = (const float*)d_in[5];
  const float* bv = (const float*)d_in[6];
  const float* wo = (const float*)d_in[7];
  const float* bo = (const float*)d_in[8];
  const int* pos = (const int*)d_in[9];
  float* out = (float*)d_out;

  char* ws = (char*)d_ws;
  // ws layout: qtmp 16MB | ktmp 8MB | vtmp 8MB = 32MB.
  // qtmp/ktmp: [b][s][head][d] (packed after rope). vtmp: [b][head][d][s]
  // (transposed, packed). attn writes fp32 output in place over q segment.
  float* qtmp = (float*)ws;
  float* ktmp = (float*)(ws + ((size_t)16 << 20));
  float* vtmp = (float*)(ws + ((size_t)24 << 20));

  dim3 blk(256);
  // Fused QKV projection: grid 32x16 = 512 blocks (2/CU)
  gemm_qkv<<<dim3(32, 16), blk, 0, stream>>>(hidden, wq, bq, wk, bk, wv, bv,
                                             qtmp, ktmp, vtmp);
  // RoPE + in-place split-pack of q, k, v
  rope_pack<<<dim3(S_, B_), dim3(256), 0, stream>>>(qtmp, ktmp, vtmp, pos);
  // MFMA sparse attention: 16 queries/block, 512 threads, grid 64x16x2
  attn_kernel<<<dim3(S_ / QB_, NH_, B_), dim3(512), 0, stream>>>(
      (unsigned*)qtmp, (const unsigned*)ktmp, (const unsigned*)vtmp);
  // Output projection: 64-row tiles -> grid 16x32 = 512 blocks (2/CU)
  gemm_split_k<2><<<dim3(H_ / 128, (B_ * S_) / 64), blk, 0, stream>>>(
      qtmp, wo, bo, out, H_, H_);
}

// Round 5
// 558.376 us; speedup vs baseline: 1.1256x; 1.1256x over previous
//
#include <hip/hip_runtime.h>
#include <hip/hip_bf16.h>

// Problem constants
constexpr int B_ = 2, S_ = 1024, H_ = 2048;
constexpr int NH_ = 16, NKV_ = 8, HD_ = 128, GROUPS_ = 2;
constexpr int TOPK_ = 409;  // int(0.4 * 1024)
constexpr int QSTRIDE = NH_ * HD_;   // 2048
constexpr int KSTRIDE = NKV_ * HD_;  // 1024
constexpr int QB_ = 16;              // queries per attention block (full MFMA M)

typedef __attribute__((ext_vector_type(8))) short short8;
typedef __attribute__((ext_vector_type(4))) float f32x4;
typedef __attribute__((ext_vector_type(4))) unsigned u32x4;
typedef __attribute__((ext_vector_type(4))) unsigned short ush4;

__device__ inline unsigned fkey(float x) {
  unsigned u = __float_as_uint(x);
  return (u & 0x80000000u) ? ~u : (u | 0x80000000u);
}
__device__ inline unsigned short bf16_rne(float x) {
  unsigned u = __float_as_uint(x);
  unsigned r = u + 0x7FFFu + ((u >> 16) & 1u);
  return (unsigned short)(r >> 16);
}
__device__ inline float bf16_to_f(unsigned short h) {
  return __uint_as_float((unsigned)h << 16);
}
// float -> (hi bf16 << 16) | lo bf16   (RNE split: x ~= hi + lo)
__device__ inline unsigned packsplit(float x) {
  unsigned u = __float_as_uint(x);
  unsigned r = (u + 0x7FFFu + ((u >> 16) & 1u)) & 0xFFFF0000u;
  float rem = x - __uint_as_float(r);
  unsigned v = __float_as_uint(rem);
  unsigned l = (v + 0x7FFFu + ((v >> 16) & 1u)) >> 16;
  return r | l;
}

// perm selectors: dst = {src1.b2,src1.b3,src0.b2,src0.b3} (hi) / low bytes (lo)
#define PERM_HI 0x07060302u
#define PERM_LO 0x05040100u

// 8 packed dwords (16B-aligned LDS/global) -> hi/lo bf16 fragments
__device__ inline void unpack8(const unsigned* p, short8& hi, short8& lo) {
  u32x4 w0 = *(const u32x4*)p;
  u32x4 w1 = *(const u32x4*)(p + 4);
  u32x4 h, l;
  h.x = __builtin_amdgcn_perm(w0.y, w0.x, PERM_HI);
  h.y = __builtin_amdgcn_perm(w0.w, w0.z, PERM_HI);
  h.z = __builtin_amdgcn_perm(w1.y, w1.x, PERM_HI);
  h.w = __builtin_amdgcn_perm(w1.w, w1.z, PERM_HI);
  l.x = __builtin_amdgcn_perm(w0.y, w0.x, PERM_LO);
  l.y = __builtin_amdgcn_perm(w0.w, w0.z, PERM_LO);
  l.z = __builtin_amdgcn_perm(w1.y, w1.x, PERM_LO);
  l.w = __builtin_amdgcn_perm(w1.w, w1.z, PERM_LO);
  hi = *(short8*)&h;
  lo = *(short8*)&l;
}
// same, from two registers (globals already loaded)
__device__ inline void unpack8r(u32x4 w0, u32x4 w1, short8& hi, short8& lo) {
  u32x4 h, l;
  h.x = __builtin_amdgcn_perm(w0.y, w0.x, PERM_HI);
  h.y = __builtin_amdgcn_perm(w0.w, w0.z, PERM_HI);
  h.z = __builtin_amdgcn_perm(w1.y, w1.x, PERM_HI);
  h.w = __builtin_amdgcn_perm(w1.w, w1.z, PERM_HI);
  l.x = __builtin_amdgcn_perm(w0.y, w0.x, PERM_LO);
  l.y = __builtin_amdgcn_perm(w0.w, w0.z, PERM_LO);
  l.z = __builtin_amdgcn_perm(w1.y, w1.x, PERM_LO);
  l.w = __builtin_amdgcn_perm(w1.w, w1.z, PERM_LO);
  hi = *(short8*)&h;
  lo = *(short8*)&l;
}

// ---------------------------------------------------------------------------
// Split-precision bf16 MFMA GEMM body: C[m,n] = sum_k A[m,k]*W[n,k] + bias[n]
// Tile: (TI*32) x 128, BK=32, 256 threads (4 waves).
// Double-buffered LDS staging, ONE barrier per K-step, register prefetch of
// step k+1 globals under step-k compute. Staging layout is chunk-swizzled
// (16B chunks, c ^= (row>>1)&3) so fragment ds_read_b128 is 2-way (free).
// ---------------------------------------------------------------------------
template <int TI>
__device__ __forceinline__ void gemm_split_body(
    const float* __restrict__ A, const float* __restrict__ W,
    const float* __restrict__ bias, float* __restrict__ C, int ldc, int c0,
    int K, int m0) {
  __shared__ unsigned short Ah[2][TI * 32 * 32];
  __shared__ unsigned short Al[2][TI * 32 * 32];
  __shared__ unsigned short Wh[2][128 * 32];
  __shared__ unsigned short Wl[2][128 * 32];
  const int tid = threadIdx.x;
  const int lane = tid & 63, wid = tid >> 6;
  const int wrow = (wid >> 1) * (TI * 16), wcol = (wid & 1) * 64;
  const int fm = lane & 15, quad = lane >> 4;
  const int srow = tid >> 3;        // 0..31
  const int skq = (tid & 7) * 4;    // 0,4,..,28
  f32x4 acc[TI][4] = {};
  float4 avr[TI], wvr[4];

  auto loadAW = [&](int k0) {
#pragma unroll
    for (int r = 0; r < TI; ++r)
      avr[r] = *(const float4*)&A[(size_t)(m0 + srow + 32 * r) * K + k0 + skq];
#pragma unroll
    for (int r = 0; r < 4; ++r)
      wvr[r] = *(const float4*)&W[(size_t)(srow + 32 * r) * K + k0 + skq];
  };
  auto convWrite = [&](int buf) {
#pragma unroll
    for (int r = 0; r < TI; ++r) {
      const int row = srow + 32 * r;
      const int off =
          row * 32 + ((((skq >> 3) ^ ((row >> 1) & 3)) << 3) | (skq & 7));
      unsigned short h0 = bf16_rne(avr[r].x), h1 = bf16_rne(avr[r].y),
                     h2 = bf16_rne(avr[r].z), h3 = bf16_rne(avr[r].w);
      ush4 hv; hv.x = h0; hv.y = h1; hv.z = h2; hv.w = h3;
      ush4 lv;
      lv.x = bf16_rne(avr[r].x - bf16_to_f(h0));
      lv.y = bf16_rne(avr[r].y - bf16_to_f(h1));
      lv.z = bf16_rne(avr[r].z - bf16_to_f(h2));
      lv.w = bf16_rne(avr[r].w - bf16_to_f(h3));
      *(ush4*)&Ah[buf][off] = hv;
      *(ush4*)&Al[buf][off] = lv;
    }
#pragma unroll
    for (int r = 0; r < 4; ++r) {
      const int row = srow + 32 * r;
      const int off =
          row * 32 + ((((skq >> 3) ^ ((row >> 1) & 3)) << 3) | (skq & 7));
      unsigned short g0 = bf16_rne(wvr[r].x), g1 = bf16_rne(wvr[r].y),
                     g2 = bf16_rne(wvr[r].z), g3 = bf16_rne(wvr[r].w);
      ush4 hv; hv.x = g0; hv.y = g1; hv.z = g2; hv.w = g3;
      ush4 lv;
      lv.x = bf16_rne(wvr[r].x - bf16_to_f(g0));
      lv.y = bf16_rne(wvr[r].y - bf16_to_f(g1));
      lv.z = bf16_rne(wvr[r].z - bf16_to_f(g2));
      lv.w = bf16_rne(wvr[r].w - bf16_to_f(g3));
      *(ush4*)&Wh[buf][off] = hv;
      *(ush4*)&Wl[buf][off] = lv;
    }
  };

  loadAW(0);
  convWrite(0);
  __syncthreads();
  int cur = 0;
  for (int k0 = 0; k0 < K; k0 += 32) {
    const bool more = (k0 + 32) < K;
    if (more) loadAW(k0 + 32);  // issue early; consumed by convWrite below
    short8 ah[TI], al[TI], bh[4], bl[4];
#pragma unroll
    for (int ti = 0; ti < TI; ++ti) {
      const int r = wrow + 16 * ti + fm;
      const int off = r * 32 + ((quad ^ ((r >> 1) & 3)) << 3);
      ah[ti] = *(const short8*)&Ah[cur][off];
      al[ti] = *(const short8*)&Al[cur][off];
    }
#pragma unroll
    for (int tj = 0; tj < 4; ++tj) {
      const int r = wcol + 16 * tj + fm;
      const int off = r * 32 + ((quad ^ ((r >> 1) & 3)) << 3);
      bh[tj] = *(const short8*)&Wh[cur][off];
      bl[tj] = *(const short8*)&Wl[cur][off];
    }
#pragma unroll
    for (int ti = 0; ti < TI; ++ti)
#pragma unroll
      for (int tj = 0; tj < 4; ++tj) {
        acc[ti][tj] = __builtin_amdgcn_mfma_f32_16x16x32_bf16(
            ah[ti], bh[tj], acc[ti][tj], 0, 0, 0);
        acc[ti][tj] = __builtin_amdgcn_mfma_f32_16x16x32_bf16(
            ah[ti], bl[tj], acc[ti][tj], 0, 0, 0);
        acc[ti][tj] = __builtin_amdgcn_mfma_f32_16x16x32_bf16(
            al[ti], bh[tj], acc[ti][tj], 0, 0, 0);
      }
    if (more) convWrite(cur ^ 1);
    __syncthreads();
    cur ^= 1;
  }
#pragma unroll
  for (int tj = 0; tj < 4; ++tj) {
    float bsv = bias[wcol + 16 * tj + fm];
#pragma unroll
    for (int ti = 0; ti < TI; ++ti) {
      int mrow = m0 + wrow + 16 * ti + quad * 4;
      int ncol = c0 + wcol + 16 * tj + fm;
#pragma unroll
      for (int reg = 0; reg < 4; ++reg)
        C[(size_t)(mrow + reg) * ldc + ncol] = acc[ti][tj][reg] + bsv;
    }
  }
}

// Fused QKV projection: N-space = [q 0..2048) [k 2048..3072) [v 3072..4096)
__global__ __launch_bounds__(256) void gemm_qkv(
    const float* __restrict__ hidden, const float* __restrict__ wq,
    const float* __restrict__ bq, const float* __restrict__ wk,
    const float* __restrict__ bk, const float* __restrict__ wv,
    const float* __restrict__ bv, float* __restrict__ q, float* __restrict__ k,
    float* __restrict__ v) {
  const int n0 = blockIdx.x * 128, m0 = blockIdx.y * 128;
  const float* W;
  const float* bias;
  float* C;
  int ldc, c0;
  if (n0 < QSTRIDE) {
    W = wq + (size_t)n0 * H_; bias = bq + n0; C = q; ldc = QSTRIDE; c0 = n0;
  } else if (n0 < QSTRIDE + KSTRIDE) {
    int nn = n0 - QSTRIDE;
    W = wk + (size_t)nn * H_; bias = bk + nn; C = k; ldc = KSTRIDE; c0 = nn;
  } else {
    int nn = n0 - QSTRIDE - KSTRIDE;
    W = wv + (size_t)nn * H_; bias = bv + nn; C = v; ldc = KSTRIDE; c0 = nn;
  }
  gemm_split_body<4>(hidden, W, bias, C, ldc, c0, H_, m0);
}

// Generic GEMM (used for out-proj with TI=2 -> 64-row tiles, grid 512)
template <int TI>
__global__ __launch_bounds__(256) void gemm_split_k(
    const float* __restrict__ A, const float* __restrict__ W,
    const float* __restrict__ bias, float* __restrict__ C, int N, int K) {
  const int n0 = blockIdx.x * 128, m0 = blockIdx.y * (TI * 32);
  gemm_split_body<TI>(A, W + (size_t)n0 * K, bias + n0, C, N, n0, K, m0);
}

// ---------------------------------------------------------------------------
// RoPE (q,k) + split-pack q,k,v IN PLACE as (hi<<16|lo) dwords.
// grid (S, B), block 256. inv_freq computed once per block (double pow,
// bit-identical) into LDS.
// ---------------------------------------------------------------------------
__global__ __launch_bounds__(256) void rope_pack(float* __restrict__ qtmp,
                                                 float* __restrict__ ktmp,
                                                 float* __restrict__ vtmp,
                                                 const int* __restrict__ pos_ids) {
  const int s = blockIdx.x, b = blockIdx.y;
  const int t = threadIdx.x;
  __shared__ float fsh[64];
  if (t < 64) fsh[t] = (float)(1.0 / pow(1.0e6, (double)t / 64.0));
  __syncthreads();
  const int pos = pos_ids[b * S_ + s];
#pragma unroll
  for (int it = 0; it < 8; ++it) {
    const int p = t + 256 * it;   // 0..2047
    const int slot = p >> 6;      // 0..31 (uniform per wave)
    const int d = p & 63;
    float* base;
    if (slot < NH_)
      base = qtmp + (size_t)(b * S_ + s) * QSTRIDE + slot * HD_;
    else if (slot < NH_ + NKV_)
      base = ktmp + (size_t)(b * S_ + s) * KSTRIDE + (slot - NH_) * HD_;
    else
      base = vtmp + (size_t)(b * S_ + s) * KSTRIDE + (slot - NH_ - NKV_) * HD_;
    float x = base[d], y = base[d + 64];
    unsigned* up = (unsigned*)base;
    if (slot < NH_ + NKV_) {
      float ang = (float)pos * fsh[d];
      float c = cosf(ang), sn = sinf(ang);
      up[d] = packsplit(x * c - y * sn);
      up[d + 64] = packsplit(y * c + x * sn);
    } else {
      up[d] = packsplit(x);
      up[d + 64] = packsplit(y);
    }
  }
}

// ---------------------------------------------------------------------------
// Sparse attention v8 (MFMA): one block per (b, h, 16 queries), 512 threads.
// K/V fragments direct from global (L2-resident). Exact top-k via 32-round
// bisection with BALLOT+POPCOUNT counting (scalar-pipe; no shuffles, no LDS
// atomics). 2 block-wide barriers. Bit-identical numerics throughout.
// ---------------------------------------------------------------------------
constexpr int SCW = 1030;   // sc row stride (pad: 1024+6)

__global__ __launch_bounds__(512, 4) void attn_kernel(
    unsigned* __restrict__ qpk, const unsigned* __restrict__ kpk,
    const unsigned* __restrict__ vpk) {
  const int q0 = blockIdx.x * QB_;
  const int h = blockIdx.y, b = blockIdx.z, g = h / GROUPS_;
  const int t = threadIdx.x, lane = t & 63, wid = t >> 6;  // wid 0..7
  const int fm = lane & 15, quad = lane >> 4;

  __shared__ float sc[QB_ * SCW];       // 65.9 KB: fp32 scores -> packed probs
  __shared__ float redmx[8][QB_];
  __shared__ float Zsh[QB_];
  const float scale = 0.08838834764831845f;  // 1/sqrt(128)

  // ---- Q A-fragments straight from global (row fm = query within block) ----
  short8 qh[4], ql[4];
  {
    const unsigned* qrow =
        qpk + (size_t)(b * S_ + q0 + fm) * QSTRIDE + h * HD_;
#pragma unroll
    for (int ks = 0; ks < 4; ++ks) {
      u32x4 a0 = *(const u32x4*)&qrow[ks * 32 + quad * 8];
      u32x4 a1 = *(const u32x4*)&qrow[ks * 32 + quad * 8 + 4];
      unpack8r(a0, a1, qh[ks], ql[ks]);
    }
  }

  // ---- QK^T over 8 tiles of 128 keys; K fragments direct from global ----
  const unsigned* kg = kpk + (size_t)(b * S_) * KSTRIDE + g * HD_;
  f32x4 mxacc = {-1e30f, -1e30f, -1e30f, -1e30f};
  for (int tile = 0; tile < 8; ++tile) {
    const unsigned* kr = kg + (size_t)(tile * 128 + wid * 16 + fm) * KSTRIDE;
    u32x4 kreg[8];
#pragma unroll
    for (int ks = 0; ks < 4; ++ks) {
      kreg[2 * ks] = *(const u32x4*)&kr[ks * 32 + quad * 8];
      kreg[2 * ks + 1] = *(const u32x4*)&kr[ks * 32 + quad * 8 + 4];
    }
    f32x4 acc = {0.f, 0.f, 0.f, 0.f};
#pragma unroll
    for (int ks = 0; ks < 4; ++ks) {
      short8 bh, bl;
      unpack8r(kreg[2 * ks], kreg[2 * ks + 1], bh, bl);
      acc = __builtin_amdgcn_mfma_f32_16x16x32_bf16(qh[ks], bh, acc, 0, 0, 0);
      acc = __builtin_amdgcn_mfma_f32_16x16x32_bf16(qh[ks], bl, acc, 0, 0, 0);
      acc = __builtin_amdgcn_mfma_f32_16x16x32_bf16(ql[ks], bh, acc, 0, 0, 0);
    }
    // C/D: col = fm (key), row = quad*4+reg (all 16 rows = queries)
    const int key = tile * 128 + wid * 16 + fm;
#pragma unroll
    for (int reg = 0; reg < 4; ++reg) {
      float sval = acc[reg] * scale;
      sc[(quad * 4 + reg) * SCW + key] = sval;
      mxacc[reg] = fmaxf(mxacc[reg], sval);
    }
  }
  // per-wave row max: reduce across fm lanes (quad bits untouched)
#pragma unroll
  for (int o = 1; o < 16; o <<= 1) {
    mxacc[0] = fmaxf(mxacc[0], __shfl_xor(mxacc[0], o));
    mxacc[1] = fmaxf(mxacc[1], __shfl_xor(mxacc[1], o));
    mxacc[2] = fmaxf(mxacc[2], __shfl_xor(mxacc[2], o));
    mxacc[3] = fmaxf(mxacc[3], __shfl_xor(mxacc[3], o));
  }
  if (fm == 0) {
#pragma unroll
    for (int reg = 0; reg < 4; ++reg) redmx[wid][quad * 4 + reg] = mxacc[reg];
  }
  __syncthreads();  // barrier 1: sc + redmx complete (all waves)

  // ---- exact top-k threshold: 32-round bisection, ballot+popcount counts ---
  // T = max{T : #(fkey >= T) >= k}  (k-th largest key; ties included)
  unsigned curA = 0u, curB = 0u;
  {
    unsigned uvA[16], uvB[16];
#pragma unroll
    for (int j = 0; j < 16; ++j)
      uvA[j] = fkey(sc[(2 * wid) * SCW + lane + 64 * j]);
#pragma unroll
    for (int j = 0; j < 16; ++j)
      uvB[j] = fkey(sc[(2 * wid + 1) * SCW + lane + 64 * j]);
    for (int bit = 31; bit >= 0; --bit) {
      const unsigned cA = curA | (1u << bit), cB = curB | (1u << bit);
      int cntA = 0, cntB = 0;
#pragma unroll
      for (int j = 0; j < 16; ++j)
        cntA += __popcll(__ballot(uvA[j] >= cA));
#pragma unroll
      for (int j = 0; j < 16; ++j)
        cntB += __popcll(__ballot(uvB[j] >= cB));
      if (cntA >= TOPK_) curA = cA;
      if (cntB >= TOPK_) curB = cB;
    }
  }
  const unsigned pref = (lane >= 32) ? curB : curA;  // row qi = t>>5

  // ---- masked softmax numerators; pack P in place as hi|lo dwords ----
  // wave wid owns sc rows 2wid, 2wid+1 (the same rows it selected).
  {
    const int qi = t >> 5, li = t & 31;  // 32 threads per query row
    const float mx =
        fmaxf(fmaxf(fmaxf(redmx[0][qi], redmx[1][qi]),
                    fmaxf(redmx[2][qi], redmx[3][qi])),
              fmaxf(fmaxf(redmx[4][qi], redmx[5][qi]),
                    fmaxf(redmx[6][qi], redmx[7][qi])));
    unsigned* scp = (unsigned*)&sc[qi * SCW];
    float zloc = 0.f;
#pragma unroll 2
    for (int j = 0; j < 8; ++j) {
      int i4 = li * 4 + 128 * j;
      f32x4 sv = *(const f32x4*)&sc[qi * SCW + i4];
      u32x4 pk;
      float p0 = (fkey(sv.x) >= pref) ? __expf(sv.x - mx) : 0.0f;
      float p1 = (fkey(sv.y) >= pref) ? __expf(sv.y - mx) : 0.0f;
      float p2 = (fkey(sv.z) >= pref) ? __expf(sv.z - mx) : 0.0f;
      float p3 = (fkey(sv.w) >= pref) ? __expf(sv.w - mx) : 0.0f;
      zloc += p0 + p1 + p2 + p3;
      pk.x = packsplit(p0); pk.y = packsplit(p1);
      pk.z = packsplit(p2); pk.w = packsplit(p3);
      *(u32x4*)&scp[i4] = pk;
    }
#pragma unroll
    for (int off = 1; off < 32; off <<= 1) zloc += __shfl_xor(zloc, off);
    if (li == 0) Zsh[qi] = zloc;
  }
  __syncthreads();  // barrier 2: packed P + Zsh visible to all waves

  // ---- P.V over 8 tiles of 128 keys; V fragments direct from global ----
  const unsigned* scp2 = (const unsigned*)sc;
  const unsigned* vg = vpk + (size_t)(b * S_) * KSTRIDE + g * HD_;
  f32x4 oacc = {0.f, 0.f, 0.f, 0.f};
  const int dim = wid * 16 + fm;  // output dim for this lane

  auto pvstep = [&](const unsigned* w, int tile, int ksv) {
    short8 ph, pl;
    unpack8(&scp2[fm * SCW + tile * 128 + ksv * 32 + quad * 8], ph, pl);
    u32x4 hq, lq;
    hq.x = __builtin_amdgcn_perm(w[1], w[0], PERM_HI);
    hq.y = __builtin_amdgcn_perm(w[3], w[2], PERM_HI);
    hq.z = __builtin_amdgcn_perm(w[5], w[4], PERM_HI);
    hq.w = __builtin_amdgcn_perm(w[7], w[6], PERM_HI);
    lq.x = __builtin_amdgcn_perm(w[1], w[0], PERM_LO);
    lq.y = __builtin_amdgcn_perm(w[3], w[2], PERM_LO);
    lq.z = __builtin_amdgcn_perm(w[5], w[4], PERM_LO);
    lq.w = __builtin_amdgcn_perm(w[7], w[6], PERM_LO);
    short8 vh = *(short8*)&hq;
    short8 vl = *(short8*)&lq;
    oacc = __builtin_amdgcn_mfma_f32_16x16x32_bf16(ph, vh, oacc, 0, 0, 0);
    oacc = __builtin_amdgcn_mfma_f32_16x16x32_bf16(ph, vl, oacc, 0, 0, 0);
    oacc = __builtin_amdgcn_mfma_f32_16x16x32_bf16(pl, vh, oacc, 0, 0, 0);
  };

  for (int tile = 0; tile < 8; ++tile) {
    const unsigned* vb0 = vg + (size_t)(tile * 128 + quad * 8) * KSTRIDE + dim;
    unsigned va[8], vb[8];
#pragma unroll
    for (int i = 0; i < 8; ++i) va[i] = vb0[(size_t)i * KSTRIDE];
#pragma unroll
    for (int i = 0; i < 8; ++i) vb[i] = vb0[(size_t)(32 + i) * KSTRIDE];
    pvstep(va, tile, 0);
#pragma unroll
    for (int i = 0; i < 8; ++i) va[i] = vb0[(size_t)(64 + i) * KSTRIDE];
    pvstep(vb, tile, 1);
#pragma unroll
    for (int i = 0; i < 8; ++i) vb[i] = vb0[(size_t)(96 + i) * KSTRIDE];
    pvstep(va, tile, 2);
    pvstep(vb, tile, 3);
  }

  // ---- epilogue: row = quad*4+reg (all 16), col = wid*16 + fm ----
#pragma unroll
  for (int reg = 0; reg < 4; ++reg) {
    const int q = quad * 4 + reg;
    const float invZ = 1.0f / Zsh[q];  // Z >= 1 structurally
    float* outp = (float*)qpk + (size_t)(b * S_ + q0 + q) * QSTRIDE + h * HD_;
    outp[dim] = oacc[reg] * invZ;
  }
}

// ---------------------------------------------------------------------------
extern "C" void kernel_launch(void* const* d_in, const int* in_sizes, int n_in,
                              void* d_out, int out_size, void* d_ws,
                              size_t ws_size, hipStream_t stream) {
  // All tensors are float32 per the reference; position_ids is int32.
  const float* hidden = (const float*)d_in[0];
  const float* wq = (const float*)d_in[1];
  const float* bq = (const float*)d_in[2];
  const float* wk = (const float*)d_in[3];
  const float* bk = (const float*)d_in[4];
  const float* wv = (const float*)d_in[5];
  const float* bv = (const float*)d_in[6];
  const float* wo = (const float*)d_in[7];
  const float* bo = (const float*)d_in[8];
  const int* pos = (const int*)d_in[9];
  float* out = (float*)d_out;

  char* ws = (char*)d_ws;
  // ws layout: qtmp 16MB | ktmp 8MB | vtmp 8MB = 32MB.
  // After rope_pack, all three hold packed (hi|lo) dwords in place.
  // attn writes fp32 output in place over its own q segment.
  float* qtmp = (float*)ws;
  float* ktmp = (float*)(ws + ((size_t)16 << 20));
  float* vtmp = (float*)(ws + ((size_t)24 << 20));

  dim3 blk(256);
  // Fused QKV projection: grid 32x16 = 512 blocks (2/CU)
  gemm_qkv<<<dim3(32, 16), blk, 0, stream>>>(hidden, wq, bq, wk, bk, wv, bv,
                                             qtmp, ktmp, vtmp);
  // RoPE + in-place split-pack of q, k, v
  rope_pack<<<dim3(S_, B_), dim3(256), 0, stream>>>(qtmp, ktmp, vtmp, pos);
  // MFMA sparse attention: 16 queries/block, 512 threads, grid 64x16x2
  attn_kernel<<<dim3(S_ / QB_, NH_, B_), dim3(512), 0, stream>>>(
      (unsigned*)qtmp, (const unsigned*)ktmp, (const unsigned*)vtmp);
  // Output projection: 64-row tiles -> grid 16x32 = 512 blocks (2/CU)
  gemm_split_k<2><<<dim3(H_ / 128, (B_ * S_) / 64), blk, 0, stream>>>(
      qtmp, wo, bo, out, H_, H_);
}